// Round 7
// baseline (1327.117 us; speedup 1.0000x reference)
//
#include <hip/hip_runtime.h>

namespace {

constexpr int NBATCH = 2048;
constexpr int NT     = 200;

typedef __bf16 bf16x8 __attribute__((ext_vector_type(8)));
typedef float  f32x16 __attribute__((ext_vector_type(16)));

struct Frag3 { bf16x8 h, m, l; };

// Exact 3-way split of fp32 into bf16 hi/mid/lo with RTNE at every stage
// (proven in round 4). hi+mid+lo represents v to ~2^-24 rel.
__device__ inline Frag3 split3_8(const float f[8]) {
  union { unsigned short us[8]; bf16x8 v; } uh, um, ul;
  #pragma unroll
  for (int e = 0; e < 8; ++e) {
    const float v = f[e];
    unsigned int hb = __float_as_uint(v);
    hb += 0x7FFFu + ((hb >> 16) & 1u);       // RTNE to bf16
    hb &= 0xFFFF0000u;
    const float r1 = v - __uint_as_float(hb);          // exact
    unsigned int mb = __float_as_uint(r1);
    mb += 0x7FFFu + ((mb >> 16) & 1u);
    mb &= 0xFFFF0000u;
    const float r2 = r1 - __uint_as_float(mb);         // exact
    unsigned int lb = __float_as_uint(r2);
    lb += 0x7FFFu + ((lb >> 16) & 1u);
    uh.us[e] = (unsigned short)(hb >> 16);
    um.us[e] = (unsigned short)(mb >> 16);
    ul.us[e] = (unsigned short)(lb >> 16);
  }
  Frag3 r; r.h = uh.v; r.m = um.v; r.l = ul.v; return r;
}

// Cross-term group (lh, hl, mm, mh, hm) — accumulate separately from hh so
// all rounding happens at ulp(2^-7|D|). Merge in fp32 VALU afterwards.
__device__ inline f32x16 mm_lo(f32x16 acc, const Frag3& a, const Frag3& b) {
  acc = __builtin_amdgcn_mfma_f32_32x32x16_bf16(a.l, b.h, acc, 0, 0, 0);
  acc = __builtin_amdgcn_mfma_f32_32x32x16_bf16(a.h, b.l, acc, 0, 0, 0);
  acc = __builtin_amdgcn_mfma_f32_32x32x16_bf16(a.m, b.m, acc, 0, 0, 0);
  acc = __builtin_amdgcn_mfma_f32_32x32x16_bf16(a.m, b.h, acc, 0, 0, 0);
  acc = __builtin_amdgcn_mfma_f32_32x32x16_bf16(a.h, b.m, acc, 0, 0, 0);
  return acc;
}
__device__ inline f32x16 mm_hh(f32x16 acc, const Frag3& a, const Frag3& b) {
  return __builtin_amdgcn_mfma_f32_32x32x16_bf16(a.h, b.h, acc, 0, 0, 0);
}

// C/D-layout regs -> B-operand Frag3 pair (lane holds rows 16h+8up+e at its
// col). One half-exchange via shfl_xor(32), then select + split.
__device__ inline void cd_to_bfrag(const f32x16 cd, const int up, Frag3 out[2]) {
  float sw[16];
  #pragma unroll
  for (int r = 0; r < 16; ++r) sw[r] = __shfl_xor(cd[r], 32, 64);
  #pragma unroll
  for (int h = 0; h < 2; ++h) {
    float f[8];
    const int base = 8 * h;
    #pragma unroll
    for (int e = 0; e < 4; ++e) {
      f[e]     = up ? sw[base + 4 + e] : cd[base + e];
      f[4 + e] = up ? cd[base + 4 + e] : sw[base + e];
    }
    out[h] = split3_8(f);
  }
}

// One wave = one batch element, 200-step backward Riccati recursion.
// R4-proven CONSISTENT algebra (every product consumes the same literal V~):
//   P   = V~^T A            (MFMA; VF-as-A-op trick)
//   BtV = B^T V~            (MFMA)          -> LDS
//   Vuu = R + BtV*B ; M2 = BtV*A            (fp32 VALU, fused loop)
//   Kg  = Vuu^-1 M2                         (shfl Gauss-Jordan + VALU)
//   ABK = A - B*Kg          (B*Kg via MFMA emul; subtraction in fp32)
//   V'  = P^T * ABK + Q     (MFMA; PF-as-A-op == literal P^T = A^T V~)
//   v'  = A^T v - Kg^T (B^T v) + Q*goal     (fp32 VALU)
// Asymmetry noise F of V~ then propagates as F' ~ Acl^T F Acl (closed loop,
// contractive). Mixing V~^T into the K-path (R5/R6) breaks this -> blowup.
// MFMA 32x32x16_bf16 layouts (verified rounds 2-4):
//   A-frag: lane holds A'[l&31][16h + 8*(l>>5) + e]
//   B-frag: lane holds B'[16h + 8*(l>>5) + e][l&31]
//   C/D   : lane holds C[(r&3) + 8*(r>>2) + 4*(l>>5)][l&31]
__global__ __launch_bounds__(64, 2) void lqr_kernel(
    const float* __restrict__ gA,   // [B,32,32]
    const float* __restrict__ gB,   // [B,32,8]
    const float* __restrict__ gQ,   // [B,32,32]
    const float* __restrict__ gR,   // [B,8,8]
    const float* __restrict__ gG,   // [B,201,32]
    float* __restrict__ outK,       // [T,B,8,32]
    float* __restrict__ outk)       // [T,B,8]
{
    __shared__ __attribute__((aligned(16))) float smem[2952];
    float* const sA   = smem;          // [32][32] (M2 loop b128 rows; v' col reads)
    float* const sQ   = smem + 1024;   // [32][32] (Q*goal; Q symmetric)
    float* const sBp  = smem + 2048;   // [32][9]  B padded
    float* const sBtV = smem + 2336;   // [8][36]  B^T V ; aliased as Kg later
    float* const sM2  = smem + 2624;   // [8][36]  BtV*A
    float* const svv  = smem + 2912;   // [32] running v
    float* const sbtv = smem + 2944;   // [8]  B^T v

    const int lane = threadIdx.x;
    const int b    = blockIdx.x;
    const int ig   = lane >> 3;        // 0..7
    const int kg   = lane & 7;         // 0..7
    const int k0   = kg << 2;
    const int jj   = lane & 31;
    const int col  = lane & 31;        // MFMA col within tile
    const int up   = lane >> 5;        // 0/1: lane-half

    const float* __restrict__ Ab = gA + (size_t)b * 1024;
    const float* __restrict__ Bb = gB + (size_t)b * 256;
    const float* __restrict__ Qb = gQ + (size_t)b * 1024;
    const float* __restrict__ Gb = gG + (size_t)b * (201 * 32);

    // ---------------- one-time staging ----------------
    #pragma unroll
    for (int m = 0; m < 4; ++m) {
        reinterpret_cast<float4*>(sA)[lane + 64 * m] =
            reinterpret_cast<const float4*>(Ab)[lane + 64 * m];
        reinterpret_cast<float4*>(sQ)[lane + 64 * m] =
            reinterpret_cast<const float4*>(Qb)[lane + 64 * m];
    }
    {
        float4 b4 = reinterpret_cast<const float4*>(Bb)[lane];
        const int fb = lane * 4;
        sBp[((fb + 0) >> 3) * 9 + ((fb + 0) & 7)] = b4.x;
        sBp[((fb + 1) >> 3) * 9 + ((fb + 1) & 7)] = b4.y;
        sBp[((fb + 2) >> 3) * 9 + ((fb + 2) & 7)] = b4.z;
        sBp[((fb + 3) >> 3) * 9 + ((fb + 3) & 7)] = b4.w;
    }
    const float rreg = gR[(size_t)b * 64 + lane];   // R[ig][kg]

    // AtF: A-frag of A^T AND B-frag of A (both read A[k][col]).
    Frag3 AtF[2];
    #pragma unroll
    for (int h = 0; h < 2; ++h) {
        float f[8];
        #pragma unroll
        for (int e = 0; e < 8; ++e) f[e] = Ab[(16 * h + 8 * up + e) * 32 + col];
        AtF[h] = split3_8(f);
    }
    // B^T zero-padded to 32x32 as A-frag
    Frag3 BtF[2];
    #pragma unroll
    for (int h = 0; h < 2; ++h) {
        float f[8];
        #pragma unroll
        for (int e = 0; e < 8; ++e)
            f[e] = (col < 8) ? Bb[(16 * h + 8 * up + e) * 8 + col] : 0.f;
        BtF[h] = split3_8(f);
    }
    // B as A-operand for B*Kg (32x8 in one K=16 tile: k=8up+e, up=1 half zero)
    Frag3 BFa;
    {
        float f[8];
        #pragma unroll
        for (int e = 0; e < 8; ++e) f[e] = up ? 0.f : Bb[col * 8 + e];
        BFa = split3_8(f);
    }
    // A and Q in C/D layout (register-resident addends)
    f32x16 afr, qfr;
    #pragma unroll
    for (int r = 0; r < 16; ++r) {
        const int row = (r & 3) + 8 * (r >> 2) + 4 * up;
        afr[r] = Ab[row * 32 + col];
        qfr[r] = Qb[row * 32 + col];
    }

    {   // v0 = Q * goals[:, T, :]  (Q symmetric -> column dot == row dot)
        const float* __restrict__ gl = Gb + 200 * 32;
        float t = 0.f;
        #pragma unroll
        for (int m = 0; m < 32; ++m) t += sQ[m * 32 + jj] * gl[m];
        if (lane < 32) svv[jj] = t;
    }

    f32x16 vacc = qfr;   // V0 = Q, held in C/D layout across steps

    for (int c = 0; c < NT; ++c) {
        const int step = NT - 1 - c;
        const float* __restrict__ grow = Gb + step * 32;

        // t2 = (Q * goal_step)[jj] — independent, issued early
        float t2 = 0.f;
        #pragma unroll
        for (int m = 0; m < 32; ++m) t2 += sQ[m * 32 + jj] * grow[m];

        // ---- V (C/D regs) -> frag (B-frag layout)
        Frag3 VF[2];
        cd_to_bfrag(vacc, up, VF);

        // ---- BtV = (B^T pad) V~ (1-acc small-first), then P = V~^T A
        f32x16 bacc, pC, pB;
        #pragma unroll
        for (int r = 0; r < 16; ++r) { bacc[r] = 0.f; pC[r] = 0.f; pB[r] = 0.f; }
        bacc = mm_lo(bacc, BtF[0], VF[0]);
        bacc = mm_lo(bacc, BtF[1], VF[1]);
        bacc = mm_hh(bacc, BtF[0], VF[0]);
        bacc = mm_hh(bacc, BtF[1], VF[1]);
        pC = mm_lo(pC, VF[0], AtF[0]);
        pC = mm_lo(pC, VF[1], AtF[1]);
        pB = mm_hh(pB, VF[0], AtF[0]);
        pB = mm_hh(pB, VF[1], AtF[1]);

        // ---- btv[u] = sum_j B[j][u] * v[j] (VALU; overlaps MFMAs)
        {
            const int u = lane & 7, q = lane >> 3;
            float p = 0.f;
            #pragma unroll
            for (int j = 0; j < 4; ++j) p += sBp[(4 * q + j) * 9 + u] * svv[4 * q + j];
            p += __shfl_xor(p, 8, 64);
            p += __shfl_xor(p, 16, 64);
            p += __shfl_xor(p, 32, 64);
            if (lane < 8) sbtv[u] = p;
        }

        // ---- BtV rows 0..7 -> LDS
        #pragma unroll
        for (int q = 0; q < 4; ++q)
            sBtV[(q + 4 * up) * 36 + col] = bacc[q];

        // ---- fused fp32 loop: M2 = BtV*A ; Vuu = R + BtV*B (consistent V~;
        //      overlaps the P MFMAs still in flight)
        float cur, cur8;
        {
            float m20 = 0, m21 = 0, m22 = 0, m23 = 0, vu = rreg;
            #pragma unroll
            for (int j = 0; j < 32; ++j) {
                const float  btvj = sBtV[ig * 36 + j];
                const float4 a4   = *reinterpret_cast<const float4*>(&sA[j * 32 + k0]);
                const float  bk   = sBp[j * 9 + kg];
                m20 += btvj * a4.x; m21 += btvj * a4.y;
                m22 += btvj * a4.z; m23 += btvj * a4.w;
                vu  += btvj * bk;
            }
            *reinterpret_cast<float4*>(&sM2[ig * 36 + k0]) = make_float4(m20, m21, m22, m23);
            cur  = vu;
            cur8 = (ig == kg) ? 1.f : 0.f;
        }

        // ---- Gauss-Jordan inverse of Vuu in registers via shfl.
        // Lane (ig,kg) holds [Vuu|I][ig][kg]. PD with diag>=1 -> no pivoting.
        #pragma unroll
        for (int p = 0; p < 8; ++p) {
            const float piv = __shfl(cur, p * 8 + p, 64);
            const float rp  = 1.0f / piv;
            const float pc  = __shfl(cur,  p * 8 + kg, 64);
            const float pc8 = __shfl(cur8, p * 8 + kg, 64);
            const float mrp = __shfl(cur,  ig * 8 + p, 64);
            const float fgj = mrp * rp;
            const bool  isp = (ig == p);
            cur  = isp ? pc  * rp : cur  - fgj * pc;
            cur8 = isp ? pc8 * rp : cur8 - fgj * pc8;
        }

        // ---- merge P, build P frag (B-frag layout; as A-op it is P^T = A^T V~)
        f32x16 pM;
        #pragma unroll
        for (int r = 0; r < 16; ++r) pM[r] = pC[r] + pB[r];
        Frag3 PF[2];
        cd_to_bfrag(pM, up, PF);

        // ---- P3: Kg = Vuu_inv * M2 ; kf = Vuu_inv * btv ; write outputs
        float* const sKg = sBtV;   // BtV dead after the fused loop
        {
            float ka0 = 0, ka1 = 0, ka2 = 0, ka3 = 0, kfv = 0;
            #pragma unroll
            for (int u2 = 0; u2 < 8; ++u2) {
                const float  w  = __shfl(cur8, ig * 8 + u2, 64);   // inv[ig][u2]
                const float4 m4 = *reinterpret_cast<const float4*>(&sM2[u2 * 36 + k0]);
                const float  bt = sbtv[u2];
                ka0 += w * m4.x; ka1 += w * m4.y; ka2 += w * m4.z; ka3 += w * m4.w;
                kfv += w * bt;
            }
            *reinterpret_cast<float4*>(&sKg[ig * 36 + k0]) = make_float4(ka0, ka1, ka2, ka3);
            const size_t ob = (size_t)step * NBATCH + b;
            *reinterpret_cast<float4*>(&outK[ob * 256 + ig * 32 + k0]) =
                make_float4(ka0, ka1, ka2, ka3);
            if (kg == 0) outk[ob * 8 + ig] = kfv;
        }

        // ---- Kg as B-operand (one K=16 tile: rows 8up+e; up=1 half zero)
        Frag3 KgF;
        {
            float fk[8];
            #pragma unroll
            for (int e = 0; e < 8; ++e)
                fk[e] = up ? 0.f : sKg[e * 36 + col];
            KgF = split3_8(fk);
        }

        // ---- BKg = B * Kg (emulated, 2-acc); ABK = A - BKg in fp32 (C/D regs)
        f32x16 bkC, bkB;
        #pragma unroll
        for (int r = 0; r < 16; ++r) { bkC[r] = 0.f; bkB[r] = 0.f; }
        bkC = mm_lo(bkC, BFa, KgF);
        bkB = mm_hh(bkB, BFa, KgF);
        f32x16 abk;
        #pragma unroll
        for (int r = 0; r < 16; ++r) abk[r] = afr[r] - (bkC[r] + bkB[r]);

        // ---- KF: ABK as B-frag (from registers; no LDS roundtrip)
        Frag3 KF[2];
        cd_to_bfrag(abk, up, KF);

        // ---- V' = P^T * ABK + Q (PF as A-op; 2-acc; Q added last in fp32)
        f32x16 vC, vB;
        #pragma unroll
        for (int r = 0; r < 16; ++r) { vC[r] = 0.f; vB[r] = 0.f; }
        vC = mm_lo(vC, PF[0], KF[0]);
        vC = mm_lo(vC, PF[1], KF[1]);
        vB = mm_hh(vB, PF[0], KF[0]);
        vB = mm_hh(vB, PF[1], KF[1]);

        // ---- v' = A^T v - Kg^T btv + Q*goal (VALU; overlaps V' MFMAs)
        {
            float t1 = 0.f;
            #pragma unroll
            for (int m = 0; m < 32; ++m) t1 += sA[m * 32 + jj] * svv[m];
            float tk = 0.f;
            #pragma unroll
            for (int u = 0; u < 8; ++u) tk += sKg[u * 36 + jj] * sbtv[u];
            if (lane < 32) svv[jj] = (t1 - tk) + t2;
        }

        // ---- final merge: small terms first, Q last in fp32
        #pragma unroll
        for (int r = 0; r < 16; ++r) vacc[r] = (vC[r] + vB[r]) + qfr[r];
    }
}

}  // namespace

extern "C" void kernel_launch(void* const* d_in, const int* in_sizes, int n_in,
                              void* d_out, int out_size, void* d_ws, size_t ws_size,
                              hipStream_t stream) {
    const float* A = (const float*)d_in[0];
    const float* B = (const float*)d_in[1];
    const float* Q = (const float*)d_in[2];
    const float* R = (const float*)d_in[3];
    const float* G = (const float*)d_in[4];
    float* outK = (float*)d_out;
    float* outk = outK + (size_t)NT * NBATCH * 8 * 32;
    lqr_kernel<<<dim3(NBATCH), dim3(64), 0, stream>>>(A, B, Q, R, G, outK, outk);
}

// Round 8
// 1131.115 us; speedup vs baseline: 1.1733x; 1.1733x over previous
//
#include <hip/hip_runtime.h>

namespace {

constexpr int NBATCH = 2048;
constexpr int NT     = 200;

typedef __bf16 bf16x8 __attribute__((ext_vector_type(8)));
typedef float  f32x16 __attribute__((ext_vector_type(16)));

struct Frag3 { bf16x8 h, m, l; };

// Exact 3-way split of fp32 into bf16 hi/mid/lo. Hi stage: manual RTNE
// (proven R4/R7). Mid/lo: hardware __bf16 cvt (RTNE on gfx950); residuals
// r1 = v - hi, r2 = r1 - mid remain exact in fp32. hi+mid+lo ~ v to 2^-24.
__device__ inline Frag3 split3_8(const float f[8]) {
  Frag3 r;
  #pragma unroll
  for (int e = 0; e < 8; ++e) {
    const float v = f[e];
    unsigned int hb = __float_as_uint(v);
    hb += 0x7FFFu + ((hb >> 16) & 1u);       // RTNE to bf16 (manual, proven)
    hb &= 0xFFFF0000u;
    const float hf = __uint_as_float(hb);
    const float r1 = v - hf;                 // exact
    const __bf16 mB = (__bf16)r1;            // hw RTNE cvt
    const float r2 = r1 - (float)mB;         // exact
    const __bf16 lB = (__bf16)r2;
    r.h[e] = (__bf16)hf;                     // exact (hf is bf16-representable)
    r.m[e] = mB;
    r.l[e] = lB;
  }
  return r;
}

// Cross-term group (lh, hl, mm, mh, hm) — accumulate separately from hh so
// all rounding happens at ulp(2^-7|D|). Merge in fp32 VALU afterwards.
__device__ inline f32x16 mm_lo(f32x16 acc, const Frag3& a, const Frag3& b) {
  acc = __builtin_amdgcn_mfma_f32_32x32x16_bf16(a.l, b.h, acc, 0, 0, 0);
  acc = __builtin_amdgcn_mfma_f32_32x32x16_bf16(a.h, b.l, acc, 0, 0, 0);
  acc = __builtin_amdgcn_mfma_f32_32x32x16_bf16(a.m, b.m, acc, 0, 0, 0);
  acc = __builtin_amdgcn_mfma_f32_32x32x16_bf16(a.m, b.h, acc, 0, 0, 0);
  acc = __builtin_amdgcn_mfma_f32_32x32x16_bf16(a.h, b.m, acc, 0, 0, 0);
  return acc;
}
__device__ inline f32x16 mm_hh(f32x16 acc, const Frag3& a, const Frag3& b) {
  return __builtin_amdgcn_mfma_f32_32x32x16_bf16(a.h, b.h, acc, 0, 0, 0);
}

// C/D-layout regs -> B-operand Frag3 pair. One half-exchange via
// shfl_xor(32), then select + split.
__device__ inline void cd_to_bfrag(const f32x16 cd, const int up, Frag3 out[2]) {
  float sw[16];
  #pragma unroll
  for (int r = 0; r < 16; ++r) sw[r] = __shfl_xor(cd[r], 32, 64);
  #pragma unroll
  for (int h = 0; h < 2; ++h) {
    float f[8];
    const int base = 8 * h;
    #pragma unroll
    for (int e = 0; e < 4; ++e) {
      f[e]     = up ? sw[base + 4 + e] : cd[base + e];
      f[4 + e] = up ? cd[base + 4 + e] : sw[base + e];
    }
    out[h] = split3_8(f);
  }
}

// Precompute QG[b][t][j] = (Q_b * goal_t)[j] for t = 0..200.
// Same ascending-m FMA chain as the in-loop version -> bit-identical.
__global__ __launch_bounds__(64) void qg_kernel(
    const float* __restrict__ gQ, const float* __restrict__ gG,
    float* __restrict__ QG)
{
    __shared__ float sQ[1024];
    const int lane = threadIdx.x;
    const int b    = blockIdx.x;
    const float* __restrict__ Qb = gQ + (size_t)b * 1024;
    const float* __restrict__ Gb = gG + (size_t)b * (201 * 32);
    float* __restrict__ QGb = QG + (size_t)b * (201 * 32);
    #pragma unroll
    for (int m = 0; m < 4; ++m)
        reinterpret_cast<float4*>(sQ)[lane + 64 * m] =
            reinterpret_cast<const float4*>(Qb)[lane + 64 * m];
    const int jj = lane & 31, th = lane >> 5;
    for (int t = th; t < 201; t += 2) {
        const float* __restrict__ g = Gb + t * 32;
        float acc = 0.f;
        #pragma unroll
        for (int m = 0; m < 32; ++m) acc += sQ[m * 32 + jj] * g[m];
        QGb[t * 32 + jj] = acc;
    }
}

// One wave = one batch element, 200-step backward Riccati recursion.
// R4/R7-proven CONSISTENT algebra (every product consumes the same literal V~):
//   P   = V~^T A  (MFMA, VF-as-A-op) ; BtV = B^T V~ (MFMA) -> LDS
//   Vuu = R + BtV*B ; M2 = BtV*A  (fp32 VALU fused loop)
//   Kg  = Vuu^-1 M2 (shfl Gauss-Jordan) ; ABK = A - B*Kg (fp32 cancel FIRST)
//   V'  = P^T * ABK + Q (MFMA, PF-as-A-op = literal P^T = A^T V~)
//   v'  = A^T v - Kg^T (B^T v) + QG[step]
// MFMA 32x32x16_bf16 layouts (verified rounds 2-4):
//   A-frag: lane holds A'[l&31][16h + 8*(l>>5) + e]
//   B-frag: lane holds B'[16h + 8*(l>>5) + e][l&31]
//   C/D   : lane holds C[(r&3) + 8*(r>>2) + 4*(l>>5)][l&31]
template <bool USE_QG>
__global__ __launch_bounds__(64, 2) void lqr_kernel(
    const float* __restrict__ gA,   // [B,32,32]
    const float* __restrict__ gB,   // [B,32,8]
    const float* __restrict__ gQ,   // [B,32,32]
    const float* __restrict__ gR,   // [B,8,8]
    const float* __restrict__ gG,   // [B,201,32]
    const float* __restrict__ gQG,  // [B,201,32] precomputed Q*goal (or null)
    float* __restrict__ outK,       // [T,B,8,32]
    float* __restrict__ outk)       // [T,B,8]
{
    __shared__ __attribute__((aligned(16))) float smem[4104];
    float* const sA   = smem;          // [32][32] row-major (M2 loop b128 rows)
    float* const sQ   = smem + 1024;   // [32][32] (fallback Q*goal only)
    float* const sAt  = smem + 2048;   // [32][36] A^T, pad 36 (v' b128 rows)
    float* const sBp  = smem + 3200;   // [32][9]  B padded
    float* const sBtV = smem + 3488;   // [8][36]  B^T V ; aliased as Kg later
    float* const sM2  = smem + 3776;   // [8][36]  BtV*A
    float* const svv  = smem + 4064;   // [32] running v
    float* const sbtv = smem + 4096;   // [8]  B^T v

    const int lane = threadIdx.x;
    const int b    = blockIdx.x;
    const int ig   = lane >> 3;        // 0..7
    const int kg   = lane & 7;         // 0..7
    const int k0   = kg << 2;
    const int jj   = lane & 31;
    const int col  = lane & 31;        // MFMA col within tile
    const int up   = lane >> 5;        // 0/1: lane-half

    const float* __restrict__ Ab = gA + (size_t)b * 1024;
    const float* __restrict__ Bb = gB + (size_t)b * 256;
    const float* __restrict__ Qb = gQ + (size_t)b * 1024;
    const float* __restrict__ Gb = gG + (size_t)b * (201 * 32);
    const float* __restrict__ QGb = USE_QG ? gQG + (size_t)b * (201 * 32) : nullptr;

    // ---------------- one-time staging ----------------
    #pragma unroll
    for (int m = 0; m < 4; ++m)
        reinterpret_cast<float4*>(sA)[lane + 64 * m] =
            reinterpret_cast<const float4*>(Ab)[lane + 64 * m];
    if constexpr (!USE_QG) {
        #pragma unroll
        for (int m = 0; m < 4; ++m)
            reinterpret_cast<float4*>(sQ)[lane + 64 * m] =
                reinterpret_cast<const float4*>(Qb)[lane + 64 * m];
    }
    // A^T tile for the v' row-major b128 reads
    #pragma unroll
    for (int t = 0; t < 16; ++t) {
        const int mm = 2 * t + up;
        sAt[col * 36 + mm] = Ab[mm * 32 + col];
    }
    {
        float4 b4 = reinterpret_cast<const float4*>(Bb)[lane];
        const int fb = lane * 4;
        sBp[((fb + 0) >> 3) * 9 + ((fb + 0) & 7)] = b4.x;
        sBp[((fb + 1) >> 3) * 9 + ((fb + 1) & 7)] = b4.y;
        sBp[((fb + 2) >> 3) * 9 + ((fb + 2) & 7)] = b4.z;
        sBp[((fb + 3) >> 3) * 9 + ((fb + 3) & 7)] = b4.w;
    }
    const float rreg = gR[(size_t)b * 64 + lane];   // R[ig][kg]

    // AtF: A-frag of A^T AND B-frag of A (both read A[k][col]).
    Frag3 AtF[2];
    #pragma unroll
    for (int h = 0; h < 2; ++h) {
        float f[8];
        #pragma unroll
        for (int e = 0; e < 8; ++e) f[e] = Ab[(16 * h + 8 * up + e) * 32 + col];
        AtF[h] = split3_8(f);
    }
    // B^T zero-padded to 32x32 as A-frag
    Frag3 BtF[2];
    #pragma unroll
    for (int h = 0; h < 2; ++h) {
        float f[8];
        #pragma unroll
        for (int e = 0; e < 8; ++e)
            f[e] = (col < 8) ? Bb[(16 * h + 8 * up + e) * 8 + col] : 0.f;
        BtF[h] = split3_8(f);
    }
    // B as A-operand for B*Kg (32x8 in one K=16 tile: k=8up+e, up=1 half zero)
    Frag3 BFa;
    {
        float f[8];
        #pragma unroll
        for (int e = 0; e < 8; ++e) f[e] = up ? 0.f : Bb[col * 8 + e];
        BFa = split3_8(f);
    }
    // A and Q in C/D layout (register-resident addends)
    f32x16 afr, qfr;
    #pragma unroll
    for (int r = 0; r < 16; ++r) {
        const int row = (r & 3) + 8 * (r >> 2) + 4 * up;
        afr[r] = Ab[row * 32 + col];
        qfr[r] = Qb[row * 32 + col];
    }

    // v0 = Q * goals[:, T, :]
    if constexpr (USE_QG) {
        if (lane < 32) svv[jj] = QGb[200 * 32 + jj];
    } else {
        const float* __restrict__ gl = Gb + 200 * 32;
        float t = 0.f;
        #pragma unroll
        for (int m = 0; m < 32; ++m) t += sQ[m * 32 + jj] * gl[m];
        if (lane < 32) svv[jj] = t;
    }

    f32x16 vacc = qfr;   // V0 = Q, held in C/D layout across steps
    const float* __restrict__ qgp = USE_QG ? QGb + 199 * 32 : nullptr;

    for (int c = 0; c < NT; ++c) {
        const int step = NT - 1 - c;

        // t2 = (Q * goal_step)[jj] — one coalesced load (or fallback loop)
        float t2;
        if constexpr (USE_QG) {
            t2 = qgp[jj];
        } else {
            const float* __restrict__ grow = Gb + step * 32;
            t2 = 0.f;
            #pragma unroll
            for (int m = 0; m < 32; ++m) t2 += sQ[m * 32 + jj] * grow[m];
        }

        // ---- V (C/D regs) -> frag (B-frag layout)
        Frag3 VF[2];
        cd_to_bfrag(vacc, up, VF);

        // ---- BtV = (B^T pad) V~ (1-acc small-first), then P = V~^T A
        f32x16 bacc, pC, pB;
        #pragma unroll
        for (int r = 0; r < 16; ++r) { bacc[r] = 0.f; pC[r] = 0.f; pB[r] = 0.f; }
        bacc = mm_lo(bacc, BtF[0], VF[0]);
        bacc = mm_lo(bacc, BtF[1], VF[1]);
        bacc = mm_hh(bacc, BtF[0], VF[0]);
        bacc = mm_hh(bacc, BtF[1], VF[1]);
        pC = mm_lo(pC, VF[0], AtF[0]);
        pC = mm_lo(pC, VF[1], AtF[1]);
        pB = mm_hh(pB, VF[0], AtF[0]);
        pB = mm_hh(pB, VF[1], AtF[1]);

        // ---- btv[u] = sum_j B[j][u] * v[j] (VALU; overlaps MFMAs)
        {
            const int u = lane & 7, q8 = lane >> 3;
            const float4 v4 = *reinterpret_cast<const float4*>(&svv[4 * q8]);
            float p = 0.f;
            p += sBp[(4 * q8 + 0) * 9 + u] * v4.x;
            p += sBp[(4 * q8 + 1) * 9 + u] * v4.y;
            p += sBp[(4 * q8 + 2) * 9 + u] * v4.z;
            p += sBp[(4 * q8 + 3) * 9 + u] * v4.w;
            p += __shfl_xor(p, 8, 64);
            p += __shfl_xor(p, 16, 64);
            p += __shfl_xor(p, 32, 64);
            if (lane < 8) sbtv[u] = p;
        }

        // ---- BtV rows 0..7 -> LDS
        #pragma unroll
        for (int q = 0; q < 4; ++q)
            sBtV[(q + 4 * up) * 36 + col] = bacc[q];

        // ---- fused fp32 loop: M2 = BtV*A ; Vuu = R + BtV*B (consistent V~)
        float cur, cur8;
        {
            float m20 = 0, m21 = 0, m22 = 0, m23 = 0, vu = rreg;
            #pragma unroll
            for (int jb = 0; jb < 8; ++jb) {
                const float4 bt4 = *reinterpret_cast<const float4*>(&sBtV[ig * 36 + 4 * jb]);
                #pragma unroll
                for (int q = 0; q < 4; ++q) {
                    const int j = 4 * jb + q;
                    const float btvj = (q == 0) ? bt4.x : (q == 1) ? bt4.y
                                     : (q == 2) ? bt4.z : bt4.w;
                    const float4 a4 = *reinterpret_cast<const float4*>(&sA[j * 32 + k0]);
                    const float  bk = sBp[j * 9 + kg];
                    m20 += btvj * a4.x; m21 += btvj * a4.y;
                    m22 += btvj * a4.z; m23 += btvj * a4.w;
                    vu  += btvj * bk;
                }
            }
            *reinterpret_cast<float4*>(&sM2[ig * 36 + k0]) = make_float4(m20, m21, m22, m23);
            cur  = vu;
            cur8 = (ig == kg) ? 1.f : 0.f;
        }

        // ---- Gauss-Jordan inverse of Vuu in registers via shfl.
        // Lane (ig,kg) holds [Vuu|I][ig][kg]. PD with diag>=1 -> no pivoting.
        #pragma unroll
        for (int p = 0; p < 8; ++p) {
            const float piv = __shfl(cur, p * 8 + p, 64);
            const float rp  = 1.0f / piv;
            const float pc  = __shfl(cur,  p * 8 + kg, 64);
            const float pc8 = __shfl(cur8, p * 8 + kg, 64);
            const float mrp = __shfl(cur,  ig * 8 + p, 64);
            const float fgj = mrp * rp;
            const bool  isp = (ig == p);
            cur  = isp ? pc  * rp : cur  - fgj * pc;
            cur8 = isp ? pc8 * rp : cur8 - fgj * pc8;
        }

        // ---- merge P, build P frag (B-frag layout; as A-op it is P^T = A^T V~)
        f32x16 pM;
        #pragma unroll
        for (int r = 0; r < 16; ++r) pM[r] = pC[r] + pB[r];
        Frag3 PF[2];
        cd_to_bfrag(pM, up, PF);

        // ---- P3: Kg = Vuu_inv * M2 ; kf = Vuu_inv * btv ; write outputs
        float* const sKg = sBtV;   // BtV dead after the fused loop
        {
            float ka0 = 0, ka1 = 0, ka2 = 0, ka3 = 0, kfv = 0;
            #pragma unroll
            for (int u2 = 0; u2 < 8; ++u2) {
                const float  w  = __shfl(cur8, ig * 8 + u2, 64);   // inv[ig][u2]
                const float4 m4 = *reinterpret_cast<const float4*>(&sM2[u2 * 36 + k0]);
                const float  bt = sbtv[u2];
                ka0 += w * m4.x; ka1 += w * m4.y; ka2 += w * m4.z; ka3 += w * m4.w;
                kfv += w * bt;
            }
            *reinterpret_cast<float4*>(&sKg[ig * 36 + k0]) = make_float4(ka0, ka1, ka2, ka3);
            const size_t ob = (size_t)step * NBATCH + b;
            *reinterpret_cast<float4*>(&outK[ob * 256 + ig * 32 + k0]) =
                make_float4(ka0, ka1, ka2, ka3);
            if (kg == 0) outk[ob * 8 + ig] = kfv;
        }

        // ---- Kg as B-operand (one K=16 tile: rows 8up+e; up=1 half zero)
        Frag3 KgF;
        {
            float fk[8];
            #pragma unroll
            for (int e = 0; e < 8; ++e)
                fk[e] = up ? 0.f : sKg[e * 36 + col];
            KgF = split3_8(fk);
        }

        // ---- BKg = B * Kg (emulated, 2-acc); ABK = A - BKg in fp32 (C/D regs)
        f32x16 bkC, bkB;
        #pragma unroll
        for (int r = 0; r < 16; ++r) { bkC[r] = 0.f; bkB[r] = 0.f; }
        bkC = mm_lo(bkC, BFa, KgF);
        bkB = mm_hh(bkB, BFa, KgF);
        f32x16 abk;
        #pragma unroll
        for (int r = 0; r < 16; ++r) abk[r] = afr[r] - (bkC[r] + bkB[r]);

        // ---- KF: ABK as B-frag (from registers; no LDS roundtrip)
        Frag3 KF[2];
        cd_to_bfrag(abk, up, KF);

        // ---- V' = P^T * ABK + Q (PF as A-op; 2-acc; Q added last in fp32)
        f32x16 vC, vB;
        #pragma unroll
        for (int r = 0; r < 16; ++r) { vC[r] = 0.f; vB[r] = 0.f; }
        vC = mm_lo(vC, PF[0], KF[0]);
        vC = mm_lo(vC, PF[1], KF[1]);
        vB = mm_hh(vB, PF[0], KF[0]);
        vB = mm_hh(vB, PF[1], KF[1]);

        // ---- v' = A^T v - Kg^T btv + Q*goal (VALU; overlaps V' MFMAs)
        {
            float t1 = 0.f;
            #pragma unroll
            for (int kb = 0; kb < 8; ++kb) {
                const float4 a4 = *reinterpret_cast<const float4*>(&sAt[jj * 36 + 4 * kb]);
                const float4 v4 = *reinterpret_cast<const float4*>(&svv[4 * kb]);
                t1 += a4.x * v4.x; t1 += a4.y * v4.y;
                t1 += a4.z * v4.z; t1 += a4.w * v4.w;
            }
            float tk = 0.f;
            #pragma unroll
            for (int u = 0; u < 8; ++u) tk += sKg[u * 36 + jj] * sbtv[u];
            if (lane < 32) svv[jj] = (t1 - tk) + t2;
        }

        // ---- final merge: small terms first, Q last in fp32
        #pragma unroll
        for (int r = 0; r < 16; ++r) vacc[r] = (vC[r] + vB[r]) + qfr[r];

        if constexpr (USE_QG) qgp -= 32;
    }
}

}  // namespace

extern "C" void kernel_launch(void* const* d_in, const int* in_sizes, int n_in,
                              void* d_out, int out_size, void* d_ws, size_t ws_size,
                              hipStream_t stream) {
    const float* A = (const float*)d_in[0];
    const float* B = (const float*)d_in[1];
    const float* Q = (const float*)d_in[2];
    const float* R = (const float*)d_in[3];
    const float* G = (const float*)d_in[4];
    float* outK = (float*)d_out;
    float* outk = outK + (size_t)NT * NBATCH * 8 * 32;

    const size_t need = (size_t)NBATCH * 201 * 32 * sizeof(float);
    if (ws_size >= need) {
        float* QG = (float*)d_ws;
        qg_kernel<<<dim3(NBATCH), dim3(64), 0, stream>>>(Q, G, QG);
        lqr_kernel<true><<<dim3(NBATCH), dim3(64), 0, stream>>>(
            A, B, Q, R, G, QG, outK, outk);
    } else {
        lqr_kernel<false><<<dim3(NBATCH), dim3(64), 0, stream>>>(
            A, B, Q, R, G, nullptr, outK, outk);
    }
}